// Round 10
// baseline (637.071 us; speedup 1.0000x reference)
//
#include <hip/hip_runtime.h>
#include <hip/hip_bf16.h>

#define NB 2048
#define NF 6144
#define ND 768
#define BM 256
#define BN 192
#define BK 64
#define SPLITK 2
#define KCH (NF / SPLITK)  // 3072 per block
#define NTIL (KCH / BK)    // 48 K-tiles per block

// LDS: A 256 rows x 128 B = 32 KB; B 192 rows x 128 B = 24 KB; dbuf = 112 KB
#define ABYTES (BM * 128)
#define BBYTES (BN * 128)
#define BUFBYTES (ABYTES + BBYTES)

typedef __attribute__((ext_vector_type(8))) __bf16 bf16x8;
typedef __attribute__((ext_vector_type(4))) float f32x4;

// LDS row = 64 bf16 = 128 B. 16B-block swizzle (3-bit, measured 0 conflicts
// rounds 2-9): blk = (k>>3) ^ f(row), f(row) = (row&7)^((row>>2)&7)
__device__ __forceinline__ int swzf(int row) {
  return ((row & 7) ^ ((row >> 2) & 7)) & 7;
}
__device__ __forceinline__ char* lds_addr(char* base, int row, int k) {
  const int blk = ((k >> 3) ^ swzf(row)) & 7;
  return base + row * 128 + (blk << 4) + ((k & 7) << 1);
}

// async global->LDS, 16 B per lane. LDS dest is wave-uniform base + lane*16
// (HW rule); global src is per-lane (pre-swizzled to realize the XOR layout).
__device__ __forceinline__ void async_ld16(void* lds, const void* g) {
  __builtin_amdgcn_global_load_lds(
      (const __attribute__((address_space(1))) void*)g,
      (__attribute__((address_space(3))) void*)lds, 16, 0, 0);
}

#define LGKM0()                                            \
  do {                                                     \
    asm volatile("s_waitcnt lgkmcnt(0)" ::: "memory");     \
    __builtin_amdgcn_sched_barrier(0);                     \
  } while (0)
#define WAITVM(N) asm volatile("s_waitcnt vmcnt(" #N ")" ::: "memory")

// ---------------- prepass: acts fp32 -> bf16 into workspace ----------------
__global__ __launch_bounds__(256) void cvt_acts_kernel(
    const float* __restrict__ acts, const int* __restrict__ lidx,
    unsigned short* __restrict__ wsA) {
  const size_t n8 = (size_t)(lidx[0] + 1) * NB * NF / 8;
  const size_t stride = (size_t)gridDim.x * 256;
  for (size_t i = (size_t)blockIdx.x * 256 + threadIdx.x; i < n8; i += stride) {
    float4 a = ((const float4*)acts)[2 * i];
    float4 b = ((const float4*)acts)[2 * i + 1];
    bf16x8 h;
    h[0] = (__bf16)a.x; h[1] = (__bf16)a.y; h[2] = (__bf16)a.z; h[3] = (__bf16)a.w;
    h[4] = (__bf16)b.x; h[5] = (__bf16)b.y; h[6] = (__bf16)b.z; h[7] = (__bf16)b.w;
    ((bf16x8*)wsA)[i] = h;
  }
}

// out[b,d] = sum_l bias[l,d]  (also clears the 0xAA poison deterministically)
__global__ __launch_bounds__(256) void bias_init_kernel(
    const float* __restrict__ bias, const int* __restrict__ lidx,
    float* __restrict__ out) {
  int n = lidx[0] + 1;
  int i = blockIdx.x * 256 + threadIdx.x;
  if (i >= NB * ND) return;
  int d = i % ND;
  float s = 0.f;
  for (int l = 0; l < n; ++l) s += bias[l * ND + d];
  out[i] = s;
}

// ---------------- main GEMM: bf16 A via global_load_lds ----------------
// 256x192, 8 waves (4m x 2n), BK=64, split-K x2, LDS dbuf. Per tile:
// issue 4 A-gload_lds + 8 B-f32 loads for t+1, counted per-wave vmcnt wait
// for tile t's ops, lgkm drain, ONE barrier, then 3 MFMA phases; B cvt+store
// at tail (reg-dep wait, ~3 phases after issue).
__global__ __launch_bounds__(512, 2) void gemm_bf16a(
    const unsigned short* __restrict__ actsb, const float* __restrict__ W,
    const int* __restrict__ lidx, float* __restrict__ out, int nwg) {
  extern __shared__ char cbuf[];  // 2 * BUFBYTES

  // by-fastest decode + XCD swizzle (R8: FETCH 1.27GB -> 405MB)
  const int chunk = nwg >> 3;
  const int swz = (blockIdx.x & 7) * chunk + (blockIdx.x >> 3);
  const int by = swz & 3;  // id = by + 4*(m + 8*(ks + 2*l))
  int rem = swz >> 2;
  const int m = rem & 7; rem >>= 3;
  const int ks = rem & 1; rem >>= 1;
  const int l = rem;
  if (l > lidx[0]) return;

  const int brow = m * BM;
  const int ncol = by * BN;
  const int k0 = ks * KCH;

  const int tid = threadIdx.x;
  const int lane = tid & 63;
  const int wid = tid >> 6;
  const int wrow = (wid >> 1) * 64;
  const int wcol = (wid & 1) * 96;

  f32x4 acc[4][6];
#pragma unroll
  for (int i = 0; i < 4; ++i)
#pragma unroll
    for (int j = 0; j < 6; ++j) acc[i][j] = (f32x4){0.f, 0.f, 0.f, 0.f};

  // A async staging: issue j covers rows 8*wid + 64*j + (lane>>3); lane's
  // 16B slot p = lane&7 receives global k-block p ^ f(row) (inverse swizzle)
  const unsigned short* aSrc[4];
  int ldsAoff[4];
#pragma unroll
  for (int j = 0; j < 4; ++j) {
    const int r = 8 * wid + 64 * j + (lane >> 3);
    const int kblk = (lane & 7) ^ swzf(r);
    aSrc[j] = actsb + (size_t)l * NB * NF + (size_t)(brow + r) * NF + k0 + kblk * 8;
    ldsAoff[j] = (8 * wid + 64 * j) * 128;  // lane-independent (uniform)
  }

  // B staging (fp32 W, waves 0-5): 4 consecutive d x 8 consecutive k
  const bool bstage = tid < 384;
  const int s_bd = (tid % 48) * 4;
  const int s_bk = (tid / 48) * 8;
  const float* Bptr =
      W + (size_t)l * NF * ND + (size_t)(k0 + s_bk) * ND + (ncol + s_bd);
  float4 bv[8];

  auto AGLOADS = [&](int kt, int buf) {
    char* base = cbuf + (size_t)buf * BUFBYTES;
#pragma unroll
    for (int j = 0; j < 4; ++j)
      async_ld16(base + ldsAoff[j], aSrc[j] + kt * BK);
  };
  auto BLOADS = [&](int kb) {
    if (bstage) {
#pragma unroll
      for (int j = 0; j < 8; ++j)
        bv[j] = *(const float4*)(Bptr + (size_t)(kb + j) * ND);
    }
  };
  auto BSTORE = [&](int buf) {
    if (bstage) {
      char* cB_ = cbuf + (size_t)buf * BUFBYTES + ABYTES;
#pragma unroll
      for (int dd = 0; dd < 4; ++dd) {
        bf16x8 h;
#pragma unroll
        for (int j = 0; j < 8; ++j) h[j] = (__bf16)bv[j][dd];
        *(bf16x8*)lds_addr(cB_, s_bd + dd, s_bk) = h;
      }
    }
  };

  // ---- prologue: tile 0 ----
  AGLOADS(0, 0);
  BLOADS(0);
  BSTORE(0);  // reg-dep waits its own B loads (startup only)

  for (int t = 0; t < NTIL; ++t) {
    const int cur = t & 1;
    char* rA = cbuf + (size_t)cur * BUFBYTES;
    char* rB = rA + ABYTES;
    const bool more = (t + 1 < NTIL);

    // issue next tile's staging, then counted per-wave drain of THIS tile's
    if (more) {
      AGLOADS(t + 1, cur ^ 1);
      BLOADS((t + 1) * BK);
      if (bstage) { WAITVM(12); } else { WAITVM(4); }  // wave-uniform branch
    } else {
      WAITVM(0);
    }
    LGKM0();                        // my BSTORE(t) ds_writes drained
    __builtin_amdgcn_s_barrier();   // publish: A(t) in LDS + B(t) visible
    __builtin_amdgcn_sched_barrier(0);

    // ---- P0: aF (8 b128) + bF pair0 -> 16 MFMA ----
    bf16x8 aF[4][2];
#pragma unroll
    for (int mi = 0; mi < 4; ++mi)
#pragma unroll
      for (int s = 0; s < 2; ++s)
        aF[mi][s] = *(const bf16x8*)lds_addr(
            rA, wrow + mi * 16 + (lane & 15), s * 32 + (lane >> 4) * 8);
#pragma unroll
    for (int p = 0; p < 3; ++p) {
      bf16x8 bF[2][2];
#pragma unroll
      for (int ni = 0; ni < 2; ++ni)
#pragma unroll
        for (int s = 0; s < 2; ++s)
          bF[ni][s] = *(const bf16x8*)lds_addr(
              rB, wcol + (2 * p + ni) * 16 + (lane & 15),
              s * 32 + (lane >> 4) * 8);
      LGKM0();
      __builtin_amdgcn_s_setprio(1);
#pragma unroll
      for (int s = 0; s < 2; ++s)
#pragma unroll
        for (int mi = 0; mi < 4; ++mi)
#pragma unroll
          for (int ni = 0; ni < 2; ++ni)
            acc[mi][2 * p + ni] = __builtin_amdgcn_mfma_f32_16x16x32_bf16(
                aF[mi][s], bF[ni][s], acc[mi][2 * p + ni], 0, 0, 0);
      __builtin_amdgcn_s_setprio(0);
      __builtin_amdgcn_sched_barrier(0);
    }

    // tail: cvt+write B(t+1) (loads ~3 phases old; reg-dep vmcnt wait)
    if (more) BSTORE(cur ^ 1);
  }

  // ---- epilogue: atomic accumulate (24 blocks collide: 12L x 2K) ----
  // C/D layout (m89-verified): col = lane&15, row = (lane>>4)*4 + j
  const int orow = brow + wrow + ((lane >> 4) << 2);
  const int ocol = ncol + wcol + (lane & 15);
#pragma unroll
  for (int mi = 0; mi < 4; ++mi)
#pragma unroll
    for (int ni = 0; ni < 6; ++ni)
#pragma unroll
      for (int j = 0; j < 4; ++j)
        atomicAdd(out + (size_t)(orow + mi * 16 + j) * ND + (ocol + ni * 16),
                  acc[mi][ni][j]);
}

// ---------------- fallback (ws too small): round-8 fused kernel ----------------
__global__ __launch_bounds__(512, 2) void gemm_fused(
    const float* __restrict__ acts, const float* __restrict__ W,
    const int* __restrict__ lidx, float* __restrict__ out, int nwg) {
  extern __shared__ char cbuf[];
  const int chunk = nwg >> 3;
  const int swz = (blockIdx.x & 7) * chunk + (blockIdx.x >> 3);
  const int by = swz & 3;
  int rem = swz >> 2;
  const int m = rem & 7; rem >>= 3;
  const int ks = rem & 1; rem >>= 1;
  const int l = rem;
  if (l > lidx[0]) return;
  const int brow = m * BM, ncol = by * BN, k0 = ks * KCH;
  const int tid = threadIdx.x, lane = tid & 63, wid = tid >> 6;
  const int wrow = (wid >> 1) * 64, wcol = (wid & 1) * 96;
  f32x4 acc[4][6];
#pragma unroll
  for (int i = 0; i < 4; ++i)
#pragma unroll
    for (int j = 0; j < 6; ++j) acc[i][j] = (f32x4){0.f, 0.f, 0.f, 0.f};
  const int s_arow = tid >> 3, s_ak = (tid & 7) * 8;
  const bool bstage = tid < 384;
  const int s_bd = (tid % 48) * 4, s_bk = (tid / 48) * 8;
  const float* Aptr =
      acts + (size_t)l * NB * NF + (size_t)(brow + s_arow) * NF + k0 + s_ak;
  const float* Bptr =
      W + (size_t)l * NF * ND + (size_t)(k0 + s_bk) * ND + (ncol + s_bd);
  float4 av[4][2]; float4 bv[8];
  auto LOADS = [&](int kb) {
#pragma unroll
    for (int p = 0; p < 4; ++p) {
      av[p][0] = *(const float4*)(Aptr + (size_t)(64 * p) * NF + kb);
      av[p][1] = *(const float4*)(Aptr + (size_t)(64 * p) * NF + kb + 4);
    }
    if (bstage) {
#pragma unroll
      for (int j = 0; j < 8; ++j)
        bv[j] = *(const float4*)(Bptr + (size_t)(kb + j) * ND);
    }
  };
  auto STORE = [&](char* cA_, char* cB_) {
#pragma unroll
    for (int p = 0; p < 4; ++p) {
      bf16x8 h;
      h[0] = (__bf16)av[p][0].x; h[1] = (__bf16)av[p][0].y;
      h[2] = (__bf16)av[p][0].z; h[3] = (__bf16)av[p][0].w;
      h[4] = (__bf16)av[p][1].x; h[5] = (__bf16)av[p][1].y;
      h[6] = (__bf16)av[p][1].z; h[7] = (__bf16)av[p][1].w;
      *(bf16x8*)lds_addr(cA_, s_arow + 64 * p, s_ak) = h;
    }
    if (bstage) {
#pragma unroll
      for (int dd = 0; dd < 4; ++dd) {
        bf16x8 h;
#pragma unroll
        for (int j = 0; j < 8; ++j) h[j] = (__bf16)bv[j][dd];
        *(bf16x8*)lds_addr(cB_, s_bd + dd, s_bk) = h;
      }
    }
  };
  LOADS(0);
  STORE(cbuf, cbuf + ABYTES);
  for (int t = 0; t < NTIL; ++t) {
    const int cur = t & 1;
    char* rA = cbuf + (size_t)cur * BUFBYTES;
    char* rB = rA + ABYTES;
    char* wA = cbuf + (size_t)(cur ^ 1) * BUFBYTES;
    char* wB = wA + ABYTES;
    LGKM0();
    __builtin_amdgcn_s_barrier();
    __builtin_amdgcn_sched_barrier(0);
    if (t + 1 < NTIL) LOADS((t + 1) * BK);
    __builtin_amdgcn_sched_barrier(0);
    bf16x8 aF[4][2];
#pragma unroll
    for (int mi = 0; mi < 4; ++mi)
#pragma unroll
      for (int s = 0; s < 2; ++s)
        aF[mi][s] = *(const bf16x8*)lds_addr(
            rA, wrow + mi * 16 + (lane & 15), s * 32 + (lane >> 4) * 8);
#pragma unroll
    for (int p = 0; p < 3; ++p) {
      bf16x8 bF[2][2];
#pragma unroll
      for (int ni = 0; ni < 2; ++ni)
#pragma unroll
        for (int s = 0; s < 2; ++s)
          bF[ni][s] = *(const bf16x8*)lds_addr(
              rB, wcol + (2 * p + ni) * 16 + (lane & 15),
              s * 32 + (lane >> 4) * 8);
      LGKM0();
      __builtin_amdgcn_s_setprio(1);
#pragma unroll
      for (int s = 0; s < 2; ++s)
#pragma unroll
        for (int mi = 0; mi < 4; ++mi)
#pragma unroll
          for (int ni = 0; ni < 2; ++ni)
            acc[mi][2 * p + ni] = __builtin_amdgcn_mfma_f32_16x16x32_bf16(
                aF[mi][s], bF[ni][s], acc[mi][2 * p + ni], 0, 0, 0);
      __builtin_amdgcn_s_setprio(0);
      __builtin_amdgcn_sched_barrier(0);
    }
    if (t + 1 < NTIL) STORE(wA, wB);
  }
  const int orow = brow + wrow + ((lane >> 4) << 2);
  const int ocol = ncol + wcol + (lane & 15);
#pragma unroll
  for (int mi = 0; mi < 4; ++mi)
#pragma unroll
    for (int ni = 0; ni < 6; ++ni)
#pragma unroll
      for (int j = 0; j < 4; ++j)
        atomicAdd(out + (size_t)(orow + mi * 16 + j) * ND + (ocol + ni * 16),
                  acc[mi][ni][j]);
}

extern "C" void kernel_launch(void* const* d_in, const int* in_sizes, int n_in,
                              void* d_out, int out_size, void* d_ws, size_t ws_size,
                              hipStream_t stream) {
  const float* acts = (const float*)d_in[0];
  const float* W    = (const float*)d_in[1];
  const float* bias = (const float*)d_in[2];
  const int*   lidx = (const int*)d_in[3];
  float* out = (float*)d_out;

  const int L = in_sizes[0] / (NB * NF);               // 12
  const int nwg = (ND / BN) * (NB / BM) * SPLITK * L;  // 768 = 3 x 256 CUs
  const size_t wsNeed = (size_t)L * NB * NF * 2;       // 302 MB bf16 acts

  bias_init_kernel<<<dim3((NB * ND + 255) / 256), 256, 0, stream>>>(bias, lidx, out);

  if (ws_size >= wsNeed) {
    unsigned short* wsA = (unsigned short*)d_ws;
    cvt_acts_kernel<<<dim3(2048), 256, 0, stream>>>(acts, lidx, wsA);
    hipFuncSetAttribute((const void*)gemm_bf16a,
                        hipFuncAttributeMaxDynamicSharedMemorySize, 2 * BUFBYTES);
    gemm_bf16a<<<dim3(nwg), 512, 2 * BUFBYTES, stream>>>(wsA, W, lidx, out, nwg);
  } else {
    hipFuncSetAttribute((const void*)gemm_fused,
                        hipFuncAttributeMaxDynamicSharedMemorySize, 2 * BUFBYTES);
    gemm_fused<<<dim3(nwg), 512, 2 * BUFBYTES, stream>>>(acts, W, lidx, out, nwg);
  }
}

// Round 11
// 568.215 us; speedup vs baseline: 1.1212x; 1.1212x over previous
//
#include <hip/hip_runtime.h>
#include <hip/hip_bf16.h>

#define NB 2048
#define NF 6144
#define ND 768
#define BM 256
#define BN 192
#define BK 64
#define SPLITK 2
#define KCH (NF / SPLITK)  // 3072 per block
#define NTIL (KCH / BK)    // 48 K-tiles per block

// LDS: A 256 rows x 128 B = 32 KB; B 192 rows x 128 B = 24 KB; dbuf = 112 KB
#define ABYTES (BM * 128)
#define BBYTES (BN * 128)
#define BUFBYTES (ABYTES + BBYTES)

typedef __attribute__((ext_vector_type(8))) __bf16 bf16x8;
typedef __attribute__((ext_vector_type(4))) float f32x4;

// LDS row = 64 bf16 = 128 B. 16B-block swizzle (3-bit, measured 0 conflicts
// rounds 2-10): blk = (k>>3) ^ (row&7) ^ ((row>>2)&7)
__device__ __forceinline__ char* lds_addr(char* base, int row, int k) {
  const int blk = ((k >> 3) ^ (row & 7) ^ ((row >> 2) & 7)) & 7;
  return base + row * 128 + (blk << 4) + ((k & 7) << 1);
}

// lgkm-only drain + compiler fence (rule #18)
#define LGKM0()                                            \
  do {                                                     \
    asm volatile("s_waitcnt lgkmcnt(0)" ::: "memory");     \
    __builtin_amdgcn_sched_barrier(0);                     \
  } while (0)

// out[b,d] = sum_l bias[l,d]  (also clears the 0xAA poison deterministically)
__global__ __launch_bounds__(256) void bias_init_kernel(
    const float* __restrict__ bias, const int* __restrict__ lidx,
    float* __restrict__ out) {
  int n = lidx[0] + 1;
  int i = blockIdx.x * 256 + threadIdx.x;
  if (i >= NB * ND) return;
  int d = i % ND;
  float s = 0.f;
  for (int l = 0; l < n; ++l) s += bias[l * ND + d];
  out[i] = s;
}

// 256x192 tile, 8 waves (4m x 2n), BK=64, split-K x2, LDS double-buffer,
// ONE lgkm-only barrier per K-tile (R8 structure, best=475us).
// NEW: wave-schedule stagger. The 3 MFMA phases and 2 stores are mutually
// independent per wave; waves w and w+4 share a SIMD, so splitting the
// schedule by (wid>>2) puts one "MFMA-first" and one "rotated" wave on each
// SIMD -> LDS pipe and MFMA pipe run concurrently instead of in lockstep
// bursts (R8 counters showed serial pipe sum ~= tile time).
__global__ __launch_bounds__(512, 2) void gemm_kernel(
    const float* __restrict__ acts, const float* __restrict__ W,
    const int* __restrict__ lidx, float* __restrict__ out, int nwg) {
  extern __shared__ char cbuf[];  // 2 * BUFBYTES

  // by-fastest decode + XCD swizzle (R8: FETCH 1.27GB -> 405MB)
  const int chunk = nwg >> 3;  // 96
  const int swz = (blockIdx.x & 7) * chunk + (blockIdx.x >> 3);
  const int by = swz & 3;  // id = by + 4*(m + 8*(ks + 2*l))
  int rem = swz >> 2;
  const int m = rem & 7; rem >>= 3;
  const int ks = rem & 1; rem >>= 1;
  const int l = rem;
  if (l > lidx[0]) return;  // uniform exit before any barrier

  const int brow = m * BM;
  const int ncol = by * BN;
  const int k0 = ks * KCH;

  const int tid = threadIdx.x;
  const int lane = tid & 63;
  const int wid = tid >> 6;          // 8 waves: 4m x 2n
  const int wrow = (wid >> 1) * 64;  // 0,64,128,192
  const int wcol = (wid & 1) * 96;   // 0,96

  f32x4 acc[4][6];
#pragma unroll
  for (int i = 0; i < 4; ++i)
#pragma unroll
    for (int j = 0; j < 6; ++j) acc[i][j] = (f32x4){0.f, 0.f, 0.f, 0.f};

  // A staging: thread -> (row = tid>>3 (+64 per pass p<4), 8 consecutive k)
  const int s_arow = tid >> 3;
  const int s_ak = (tid & 7) * 8;
  // B staging: threads 0..383 (waves 0-5): (4 consecutive d, 8 consecutive k)
  const bool bstage = tid < 384;
  const int s_bd = (tid % 48) * 4;
  const int s_bk = (tid / 48) * 8;

  const float* Aptr =
      acts + (size_t)l * NB * NF + (size_t)(brow + s_arow) * NF + k0 + s_ak;
  const float* Bptr =
      W + (size_t)l * NF * ND + (size_t)(k0 + s_bk) * ND + (ncol + s_bd);

  float4 av[4][2];  // A slab regs (32 VGPR)
  float4 bv[8];     // B slab regs (32 VGPR, waves 0-5)

  auto LOADS = [&](int kb) {
#pragma unroll
    for (int p = 0; p < 4; ++p) {
      av[p][0] = *(const float4*)(Aptr + (size_t)(64 * p) * NF + kb);
      av[p][1] = *(const float4*)(Aptr + (size_t)(64 * p) * NF + kb + 4);
    }
    if (bstage) {
#pragma unroll
      for (int j = 0; j < 8; ++j)
        bv[j] = *(const float4*)(Bptr + (size_t)(kb + j) * ND);
    }
  };
  auto ASTORE = [&](char* cA_) {
#pragma unroll
    for (int p = 0; p < 4; ++p) {
      bf16x8 h;
      h[0] = (__bf16)av[p][0].x; h[1] = (__bf16)av[p][0].y;
      h[2] = (__bf16)av[p][0].z; h[3] = (__bf16)av[p][0].w;
      h[4] = (__bf16)av[p][1].x; h[5] = (__bf16)av[p][1].y;
      h[6] = (__bf16)av[p][1].z; h[7] = (__bf16)av[p][1].w;
      *(bf16x8*)lds_addr(cA_, s_arow + 64 * p, s_ak) = h;
    }
  };
  auto BSTORE = [&](char* cB_) {
    if (bstage) {
#pragma unroll
      for (int dd = 0; dd < 4; ++dd) {
        bf16x8 h;
#pragma unroll
        for (int j = 0; j < 8; ++j) h[j] = (__bf16)bv[j][dd];
        *(bf16x8*)lds_addr(cB_, s_bd + dd, s_bk) = h;
      }
    }
  };

// One MFMA phase, P must be a literal (static acc indexing, rule #20):
// read bF pair P, lgkm drain, setprio-wrapped 16-MFMA cluster.
#define PH(P)                                                              \
  do {                                                                     \
    bf16x8 bF[2][2];                                                       \
    _Pragma("unroll") for (int ni = 0; ni < 2; ++ni)                       \
      _Pragma("unroll") for (int s = 0; s < 2; ++s)                        \
        bF[ni][s] = *(const bf16x8*)lds_addr(                              \
            rB, wcol + (2 * (P) + ni) * 16 + (lane & 15),                  \
            s * 32 + (lane >> 4) * 8);                                     \
    LGKM0();                                                               \
    __builtin_amdgcn_s_setprio(1);                                         \
    _Pragma("unroll") for (int s = 0; s < 2; ++s)                          \
      _Pragma("unroll") for (int mi = 0; mi < 4; ++mi)                     \
        _Pragma("unroll") for (int ni = 0; ni < 2; ++ni)                   \
          acc[mi][2 * (P) + ni] = __builtin_amdgcn_mfma_f32_16x16x32_bf16( \
              aF[mi][s], bF[ni][s], acc[mi][2 * (P) + ni], 0, 0, 0);       \
    __builtin_amdgcn_s_setprio(0);                                         \
    __builtin_amdgcn_sched_barrier(0);                                     \
  } while (0)

  // ---- prologue: tile 0 staged into buf0 (self-waiting, once) ----
  LOADS(0);
  ASTORE(cbuf);
  BSTORE(cbuf + ABYTES);

  const bool v0 = (wid < 4);  // wave-uniform; SIMD s hosts wid s (V0) + s+4 (V1)

  for (int t = 0; t < NTIL; ++t) {
    const int cur = t & 1;
    char* rA = cbuf + (size_t)cur * BUFBYTES;
    char* rB = rA + ABYTES;
    char* wA = cbuf + (size_t)(cur ^ 1) * BUFBYTES;
    char* wB = wA + ABYTES;
    const bool more = (t + 1 < NTIL);

    // tile boundary: all stores visible + all reads done (lgkm drain);
    // global loads stay in flight across the barrier.
    LGKM0();
    __builtin_amdgcn_s_barrier();
    __builtin_amdgcn_sched_barrier(0);

    if (more) LOADS((t + 1) * BK);  // consumed >=1 phase later
    __builtin_amdgcn_sched_barrier(0);

    // aF fragments (all phases need them)
    bf16x8 aF[4][2];
#pragma unroll
    for (int mi = 0; mi < 4; ++mi)
#pragma unroll
      for (int s = 0; s < 2; ++s)
        aF[mi][s] = *(const bf16x8*)lds_addr(
            rA, wrow + mi * 16 + (lane & 15), s * 32 + (lane >> 4) * 8);

    // staggered schedules: phases/stores are per-wave independent; only the
    // tile-boundary barrier orders LDS buffer reuse (hazards unchanged).
    if (v0) {
      PH(0);
      PH(1);
      if (more) ASTORE(wA);   // A loads 2 phases old
      PH(2);
      if (more) BSTORE(wB);   // B loads 3 phases old
    } else {
      PH(1);
      if (more) ASTORE(wA);   // A loads 1 phase old
      PH(2);
      PH(0);
      if (more) BSTORE(wB);   // B loads 3 phases old
    }
  }

#undef PH

  // ---- epilogue: atomic accumulate (24 blocks collide: 12L x 2K) ----
  // C/D layout (m89-verified): col = lane&15, row = (lane>>4)*4 + j
  const int orow = brow + wrow + ((lane >> 4) << 2);
  const int ocol = ncol + wcol + (lane & 15);
#pragma unroll
  for (int mi = 0; mi < 4; ++mi)
#pragma unroll
    for (int ni = 0; ni < 6; ++ni)
#pragma unroll
      for (int j = 0; j < 4; ++j)
        atomicAdd(out + (size_t)(orow + mi * 16 + j) * ND + (ocol + ni * 16),
                  acc[mi][ni][j]);
}

extern "C" void kernel_launch(void* const* d_in, const int* in_sizes, int n_in,
                              void* d_out, int out_size, void* d_ws, size_t ws_size,
                              hipStream_t stream) {
  const float* acts = (const float*)d_in[0];
  const float* W    = (const float*)d_in[1];
  const float* bias = (const float*)d_in[2];
  const int*   lidx = (const int*)d_in[3];
  float* out = (float*)d_out;

  const int L = in_sizes[0] / (NB * NF);               // 12
  const int nwg = (ND / BN) * (NB / BM) * SPLITK * L;  // 768 = 3 x 256 CUs

  hipFuncSetAttribute((const void*)gemm_kernel,
                      hipFuncAttributeMaxDynamicSharedMemorySize, 2 * BUFBYTES);

  bias_init_kernel<<<dim3((NB * ND + 255) / 256), 256, 0, stream>>>(bias, lidx, out);
  gemm_kernel<<<dim3(nwg), 512, 2 * BUFBYTES, stream>>>(acts, W, lidx, out, nwg);
}